// Round 2
// baseline (407.753 us; speedup 1.0000x reference)
//
#include <hip/hip_runtime.h>

// Problem constants (from the reference).
#define B_  64
#define T_  60
#define K_  3
#define S0_ 80
#define S1_ 80
#define BODY_ 85

#define BT_       (B_ * T_)                       // 3840 targets
#define GT_ELEMS  (B_ * K_ * S0_ * S1_ * BODY_)   // 104,448,000 floats
#define NO_ELEMS  (B_ * K_ * S0_ * S1_)           // 1,228,800 floats
#define GT_BYTES  ((size_t)GT_ELEMS * 4)          // 417,792,000 bytes (zeros)
#define NO_V4     (NO_ELEMS / 4)                  // 307,200 float4s of ones

// ---------------------------------------------------------------------------
// Ones-fill for the no_obj_mask region: 8 float4 (128 B) per thread.
// 307,200 v4 / 8 = 38,400 threads = 150 blocks of 256.
// ---------------------------------------------------------------------------
#define ONES_PER_THREAD 8
#define ONES_THREADS (NO_V4 / ONES_PER_THREAD)   // 38,400 (exact)

__global__ __launch_bounds__(256) void yolo_ones_kernel(float4* __restrict__ no_obj) {
    int t = blockIdx.x * 256 + threadIdx.x;
    if (t >= ONES_THREADS) return;
    const float4 one = make_float4(1.0f, 1.0f, 1.0f, 1.0f);
    float4* p = no_obj + (size_t)t * ONES_PER_THREAD;
#pragma unroll
    for (int i = 0; i < ONES_PER_THREAD; ++i) p[i] = one;
}

// ---------------------------------------------------------------------------
// Scatter: one thread per (b, t) target. 3840 threads total.
// Matches XLA f32 arithmetic: no FP contraction, first-max argmax.
// ---------------------------------------------------------------------------
__global__ __launch_bounds__(256) void yolo_scatter_kernel(
        const float4* __restrict__ targets_xywh,  // (B,T,4) as float4
        const int*    __restrict__ target_cls,    // (B,T)
        const int*    __restrict__ valid,         // (B,T) bool -> int
        float*        __restrict__ out) {
#pragma clang fp contract(off)
    int idx = blockIdx.x * 256 + threadIdx.x;
    if (idx >= BT_) return;

    float4 t = targets_xywh[idx];
    float x = t.x * 80.0f;
    float y = t.y * 80.0f;
    float w = t.z * 80.0f;
    float h = t.w * 80.0f;

    // ANCHORS / STRIDE (stride = 8)
    const float aw[9] = {1.25f, 2.0f,  4.125f, 3.75f,  7.75f,  7.375f, 14.5f,  19.5f,  46.625f};
    const float ah[9] = {1.625f, 3.75f, 2.875f, 7.625f, 5.625f, 14.875f, 11.25f, 24.75f, 40.75f};

    int   best  = 0;
    float bestv = -1.0f;  // all ious >= 0, so anchor 0 always beats this
#pragma unroll
    for (int a = 0; a < 9; ++a) {
        float iw    = fminf(w, aw[a]);
        float ih    = fminf(h, ah[a]);
        float inter = iw * ih;
        inter       = fmaxf(inter, 0.0f);
        float uni   = w * h + aw[a] * ah[a] - inter;
        float iou   = inter / uni;
        if (iou > bestv) { bestv = iou; best = a; }  // strict > == first-max tiebreak
    }

    // in_scale = isin(best, {0,1,2}) & valid; otherwise the scatter drops.
    if (best >= K_) return;
    if (valid[idx] == 0) return;

    int b = idx / T_;
    int k = best;               // best % 3 == best here
    int i = (int)floorf(x);     // in [0,79] since t.x in [0,1)
    int j = (int)floorf(y);

    long gt_off = ((((long)b * K_ + k) * S0_ + j) * S1_ + i) * BODY_;
    float* p = out + gt_off;
    p[0] = x;
    p[1] = y;
    p[2] = w;
    p[3] = h;
    p[4] = 1.0f;
    p[5 + target_cls[idx]] = 1.0f;  // c = cls + 5, cls in [0,80)

    long no_off = (long)GT_ELEMS + (((long)b * K_ + k) * S0_ + j) * S1_ + i;
    out[no_off] = 0.0f;
}

extern "C" void kernel_launch(void* const* d_in, const int* in_sizes, int n_in,
                              void* d_out, int out_size, void* d_ws, size_t ws_size,
                              hipStream_t stream) {
    const float4* targets_xywh = (const float4*)d_in[0];
    const int*    target_cls   = (const int*)d_in[1];
    const int*    valid        = (const int*)d_in[2];
    float*        out          = (float*)d_out;

    // ground_true <- 0.0f via the tuned rocclr fill (graph-capturable memset).
    hipMemsetAsync(d_out, 0, GT_BYTES, stream);

    // no_obj_mask <- 1.0f (4.9 MB).
    float4* no_obj_v4 = (float4*)(out + GT_ELEMS);
    yolo_ones_kernel<<<(ONES_THREADS + 255) / 256, 256, 0, stream>>>(no_obj_v4);

    // Sparse target scatter (runs after fills in stream order).
    yolo_scatter_kernel<<<(BT_ + 255) / 256, 256, 0, stream>>>(
        targets_xywh, target_cls, valid, out);
}